// Round 14
// baseline (320.411 us; speedup 1.0000x reference)
//
#include <hip/hip_runtime.h>
#include <hip/hip_bf16.h>
#include <math.h>

typedef __bf16 bf16;
typedef __bf16 bf16x8 __attribute__((ext_vector_type(8)));
typedef __bf16 bf16x4 __attribute__((ext_vector_type(4)));
typedef __bf16 bf16x2 __attribute__((ext_vector_type(2)));
typedef float f32x4 __attribute__((ext_vector_type(4)));
typedef float f32x16 __attribute__((ext_vector_type(16)));
typedef int int4v __attribute__((ext_vector_type(4)));

static constexpr int B_ = 4, T_ = 2048, C_ = 1024, H_ = 16, D_ = 64;
static constexpr int M_ = B_ * T_;   // 8192 rows
static constexpr int NQKV = 3 * C_;  // 3072
static constexpr int K_ = C_;        // 1024 (GEMM reduction dim)

__device__ __forceinline__ bf16 to_bf16(float f) { return (bf16)f; }

// async global->LDS, 16B per lane; LDS dest = wave-uniform base + lane*16
__device__ __forceinline__ void gload_lds16(const void* g, void* l) {
  __builtin_amdgcn_global_load_lds(
      (const __attribute__((address_space(1))) void*)g,
      (__attribute__((address_space(3))) void*)l, 16, 0, 0);
}

// ---------------- fp32 -> bf16 elementwise convert (x) ----------------
__global__ void cvt_x_kernel(const float* __restrict__ in, bf16* __restrict__ out) {
  int i = (blockIdx.x * blockDim.x + threadIdx.x) * 4;
  float4 v = *reinterpret_cast<const float4*>(in + i);
  bf16x4 o;
  o[0] = to_bf16(v.x); o[1] = to_bf16(v.y); o[2] = to_bf16(v.z); o[3] = to_bf16(v.w);
  *reinterpret_cast<bf16x4*>(out + i) = o;
}

// ------------- fp32 [ROWS][COLS] -> bf16 [COLS][ROWS] transpose -------------
__global__ void transpose_cvt_kernel(const float* __restrict__ in, bf16* __restrict__ out,
                                     int ROWS, int COLS) {
  __shared__ float tile[32][33];
  int c0 = blockIdx.x * 32, r0 = blockIdx.y * 32;
  int tx = threadIdx.x, ty = threadIdx.y;  // 32 x 8
#pragma unroll
  for (int i = 0; i < 32; i += 8)
    tile[ty + i][tx] = in[(size_t)(r0 + ty + i) * COLS + c0 + tx];
  __syncthreads();
#pragma unroll
  for (int i = 0; i < 32; i += 8)
    out[(size_t)(c0 + ty + i) * ROWS + r0 + tx] = to_bf16(tile[tx][ty + i]);
}

// ---------------- bf16 MFMA GEMM v2: 128x128 tile, BK=64 ----------------
// global_load_lds w16 staging into LINEAR LDS [128][64] with XOR k-slot swizzle
// (G21: inverse-swizzled global source + swizzled ds_read; involution = XOR).
template <bool QKV>
__global__ __launch_bounds__(256) void gemm_kernel(
    const bf16* __restrict__ A, const bf16* __restrict__ Bt,
    const float* __restrict__ bias,
    bf16* __restrict__ qo, bf16* __restrict__ ko, bf16* __restrict__ vo,
    float* __restrict__ co) {
  __shared__ bf16 As[128 * 64];  // row*64 + slot*8 elems; row stride 128B
  __shared__ bf16 Bs[128 * 64];
  const int bm = blockIdx.x, bn = blockIdx.y;
  const int tid = threadIdx.x;
  const int lane = tid & 63, wave = tid >> 6;
  const int wm = wave >> 1, wn = wave & 1;  // 2x2 waves, 64x64 each
  const int l15 = lane & 15, lg = lane >> 4;
  const int l3 = lane >> 3, l7 = lane & 7;
  const int sslot = l7 ^ l3;  // source k-slot: row&7 == l3 for all staging calls

  // staging source pointers: wave stages rows [wave*32, wave*32+32), 4 calls x 8 rows
  const bf16* asrc[4];
  const bf16* bsrc[4];
#pragma unroll
  for (int j = 0; j < 4; ++j) {
    const int row = wave * 32 + j * 8 + l3;
    asrc[j] = A + (size_t)(bm * 128 + row) * K_ + sslot * 8;
    bsrc[j] = Bt + (size_t)(bn * 128 + row) * K_ + sslot * 8;
  }

  f32x4 acc[4][4] = {};

  for (int k0 = 0; k0 < K_; k0 += 64) {
#pragma unroll
    for (int j = 0; j < 4; ++j) {
      gload_lds16(asrc[j] + k0, &As[(wave * 32 + j * 8) * 64]);
      gload_lds16(bsrc[j] + k0, &Bs[(wave * 32 + j * 8) * 64]);
    }
    __syncthreads();  // drains vmcnt (global_load_lds) before reads
    bf16x8 af[4][2], bf[4][2];
#pragma unroll
    for (int m = 0; m < 4; ++m)
#pragma unroll
      for (int kk = 0; kk < 2; ++kk)
        af[m][kk] = *reinterpret_cast<const bf16x8*>(
            &As[(wm * 64 + m * 16 + l15) * 64 + (((kk * 4 + lg) ^ (l15 & 7)) * 8)]);
#pragma unroll
    for (int n = 0; n < 4; ++n)
#pragma unroll
      for (int kk = 0; kk < 2; ++kk)
        bf[n][kk] = *reinterpret_cast<const bf16x8*>(
            &Bs[(wn * 64 + n * 16 + l15) * 64 + (((kk * 4 + lg) ^ (l15 & 7)) * 8)]);
#pragma unroll
    for (int kk = 0; kk < 2; ++kk)
#pragma unroll
      for (int m = 0; m < 4; ++m)
#pragma unroll
        for (int n = 0; n < 4; ++n)
          acc[m][n] =
              __builtin_amdgcn_mfma_f32_16x16x32_bf16(af[m][kk], bf[n][kk], acc[m][n], 0, 0, 0);
    __syncthreads();  // protect LDS from next-step overwrite
  }

  const int colbase = bn * 128 + wn * 64;
  const int rowbase = bm * 128 + wm * 64;
  if (QKV) {
    const int sec = (bn * 128) >> 10;  // 0=q 1=k 2=v (block-uniform)
#pragma unroll
    for (int n = 0; n < 4; ++n) {
      const int col = colbase + n * 16 + l15;
      const float bv = bias[col];
      const int cc = col & 1023;
      const int h = cc >> 6, d = cc & 63;
#pragma unroll
      for (int m = 0; m < 4; ++m) {
        const int row0 = rowbase + m * 16 + lg * 4;
        const int b = row0 >> 11, t0 = row0 & 2047;
        if (sec == 2) {
          bf16x4 pv;
#pragma unroll
          for (int r = 0; r < 4; ++r) pv[r] = to_bf16(acc[m][n][r] + bv);
          *reinterpret_cast<bf16x4*>(&vo[((size_t)(b * 16 + h) * 64 + d) * 2048 + t0]) = pv;
        } else if (sec == 0) {
#pragma unroll
          for (int r = 0; r < 4; ++r)
            qo[((size_t)(b * 16 + h) * 2048 + t0 + r) * 64 + d] =
                to_bf16((acc[m][n][r] + bv) * 0.125f);
        } else {
#pragma unroll
          for (int r = 0; r < 4; ++r)
            ko[((size_t)(b * 16 + h) * 2048 + t0 + r) * 64 + d] = to_bf16(acc[m][n][r] + bv);
        }
      }
    }
  } else {
#pragma unroll
    for (int n = 0; n < 4; ++n) {
      const int col = colbase + n * 16 + l15;
      const float bv = bias[col];
#pragma unroll
      for (int m = 0; m < 4; ++m) {
#pragma unroll
        for (int r = 0; r < 4; ++r) {
          const int row = rowbase + m * 16 + lg * 4 + r;
          co[(size_t)row * 1024 + col] = acc[m][n][r] + bv;
        }
      }
    }
  }
}

// ---------------- causal flash attention v2.3 ----------------
// Swapped-operand 32x32x16 MFMA; softmax fully in-register; no LDS.
// v2.3: K-tile REGISTER PREFETCH (T14) — next tile's K loads issue at the top
// of the current iteration, so QK^T never waits on an exposed VMEM round-trip.
// (R12 counters: 60% no-issue cycles, MfmaUtil 10.7%, VALU 31% -> latency-bound.)
__device__ __forceinline__ int pack_bf2(float lo, float hi) {
  bf16x2 t; t[0] = (bf16)lo; t[1] = (bf16)hi;
  return __builtin_bit_cast(int, t);
}

template <int R0>
__device__ __forceinline__ bf16x8 pack_pstep(f32x16 pf, int h) {
  int a  = pack_bf2(pf[R0 + 0], pf[R0 + 1]);
  int b2 = pack_bf2(pf[R0 + 2], pf[R0 + 3]);
  int c  = pack_bf2(pf[R0 + 4], pf[R0 + 5]);
  int d2 = pack_bf2(pf[R0 + 6], pf[R0 + 7]);
  int pa = __shfl_xor(a, 32);
  int pb = __shfl_xor(b2, 32);
  int pc = __shfl_xor(c, 32);
  int pd = __shfl_xor(d2, 32);
  int4v pi = {h ? pc : a, h ? pd : b2, h ? c : pa, h ? d2 : pb};
  return __builtin_bit_cast(bf16x8, pi);
}

__global__ __launch_bounds__(256) void attn_kernel(
    const bf16* __restrict__ q, const bf16* __restrict__ k,
    const bf16* __restrict__ vT, bf16* __restrict__ o) {
  const int bid = blockIdx.x;          // 0..1023
  const int xcd = bid & 7;
  const int local = bid >> 3;          // 0..127 within XCD
  const int qt = 15 - (local >> 3);    // long-first (LPT)
  const int bh = xcd * 8 + (local & 7);  // 8 heads per XCD -> KV L2-resident
  const int tid = threadIdx.x;
  const int lane = tid & 63, w = tid >> 6;
  const int l31 = lane & 31, hi = lane >> 5;
  const char* qp = (const char*)(q + (size_t)bh * T_ * D_);
  const char* kp = (const char*)(k + (size_t)bh * T_ * D_);
  const char* vp = (const char*)(vT + (size_t)bh * D_ * T_);
  const int lofKQ = l31 * 128 + hi * 16;   // K/Q row stride 128B
  const int lofV  = l31 * 4096 + hi * 16;  // vT row stride 4096B
  const int bb = bh >> 4, hh = bh & 15;
  bf16* obase = o + (size_t)bb * T_ * C_ + hh * 64;

  const int qrow0 = qt * 128 + w * 32;
  const int qg = qrow0 + l31;

  bf16x8 qf[4];
#pragma unroll
  for (int s = 0; s < 4; ++s)
    qf[s] = *reinterpret_cast<const bf16x8*>(qp + (size_t)qrow0 * 128 + s * 32 + lofKQ);

  f32x16 ot0 = {}, ot1 = {};
  float mrun = -INFINITY, lrun = 0.f;

  // prefetch K tile 0 into registers
  bf16x8 kc0[4], kc1[4];
#pragma unroll
  for (int s = 0; s < 4; ++s) {
    kc0[s] = *reinterpret_cast<const bf16x8*>(kp + (size_t)0 * 128 + s * 32 + lofKQ);
    kc1[s] = *reinterpret_cast<const bf16x8*>(kp + (size_t)32 * 128 + s * 32 + lofKQ);
  }

  for (int tb = 0; tb < qrow0 + 32; tb += 64) {
    // issue NEXT K-tile loads first (consumed next iteration; ~full iter of latency cover)
    const int tbn = (tb + 64 <= T_ - 64) ? tb + 64 : T_ - 64;  // clamp (last-iter value unused)
    bf16x8 kn0[4], kn1[4];
#pragma unroll
    for (int s = 0; s < 4; ++s) {
      kn0[s] = *reinterpret_cast<const bf16x8*>(kp + (size_t)tbn * 128 + s * 32 + lofKQ);
      kn1[s] = *reinterpret_cast<const bf16x8*>(kp + (size_t)(tbn + 32) * 128 + s * 32 + lofKQ);
    }
    // QK^T (swapped) on CURRENT prefetched K: lane holds 32 k-values for q = l31
    f32x16 st0 = {}, st1 = {};
#pragma unroll
    for (int s = 0; s < 4; ++s) {
      st0 = __builtin_amdgcn_mfma_f32_32x32x16_bf16(kc0[s], qf[s], st0, 0, 0, 0);
      st1 = __builtin_amdgcn_mfma_f32_32x32x16_bf16(kc1[s], qf[s], st1, 0, 0, 0);
    }
    // V A-fragments: issue loads early, consumed after softmax (latency hide)
    bf16x8 va[2][4];
#pragma unroll
    for (int dt = 0; dt < 2; ++dt)
#pragma unroll
      for (int s = 0; s < 4; ++s)
        va[dt][s] = *reinterpret_cast<const bf16x8*>(
            vp + (size_t)dt * 32 * 4096 + (size_t)(tb + s * 16) * 2 + lofV);
    // causal mask (diagonal tiles only)
    if (tb + 63 > qrow0) {
#pragma unroll
      for (int r = 0; r < 16; ++r) {
        const int koff = (r & 3) + 8 * (r >> 2) + 4 * hi;
        if (tb + koff > qg) st0[r] = -1e30f;
        if (tb + 32 + koff > qg) st1[r] = -1e30f;
      }
    }
    // row max: in-register tree + partner (lane^32) combine
    float mx[16];
#pragma unroll
    for (int r = 0; r < 16; ++r) mx[r] = fmaxf(st0[r], st1[r]);
#pragma unroll
    for (int d = 8; d > 0; d >>= 1)
#pragma unroll
      for (int r = 0; r < d; ++r) mx[r] = fmaxf(mx[r], mx[r + d]);
    const float pmax = fmaxf(mx[0], __shfl_xor(mx[0], 32));
    // defer-max (T13): skip O-rescale when max growth small
    if (__any(pmax > mrun + 8.f)) {
      const float mnew = fmaxf(mrun, pmax);
      const float corr = __expf(mrun - mnew);
      lrun *= corr;
#pragma unroll
      for (int r = 0; r < 16; ++r) { ot0[r] *= corr; ot1[r] *= corr; }
      mrun = mnew;
    }
#pragma unroll
    for (int r = 0; r < 16; ++r) {
      st0[r] = __expf(st0[r] - mrun);
      st1[r] = __expf(st1[r] - mrun);
    }
    // row sum: in-register tree + partner combine
    float sm[16];
#pragma unroll
    for (int r = 0; r < 16; ++r) sm[r] = st0[r] + st1[r];
#pragma unroll
    for (int d = 8; d > 0; d >>= 1)
#pragma unroll
      for (int r = 0; r < d; ++r) sm[r] += sm[r + d];
    lrun += sm[0] + __shfl_xor(sm[0], 32);
    // P -> bf16 B-fragments (pack + lane^32 exchange, no LDS)
    bf16x8 pb[4];
    pb[0] = pack_pstep<0>(st0, hi);
    pb[1] = pack_pstep<8>(st0, hi);
    pb[2] = pack_pstep<0>(st1, hi);
    pb[3] = pack_pstep<8>(st1, hi);
    // PV: O^T[d][q] — output column = q = l31, same as softmax state
#pragma unroll
    for (int s = 0; s < 4; ++s) {
      ot0 = __builtin_amdgcn_mfma_f32_32x32x16_bf16(va[0][s], pb[s], ot0, 0, 0, 0);
      ot1 = __builtin_amdgcn_mfma_f32_32x32x16_bf16(va[1][s], pb[s], ot1, 0, 0, 0);
    }
    // rotate prefetch registers
#pragma unroll
    for (int s = 0; s < 4; ++s) { kc0[s] = kn0[s]; kc1[s] = kn1[s]; }
  }

  const float inv = 1.f / lrun;
  bf16* orow = obase + (size_t)qg * C_;
#pragma unroll
  for (int dt = 0; dt < 2; ++dt) {
#pragma unroll
    for (int rg = 0; rg < 4; ++rg) {
      bf16x4 pv;
#pragma unroll
      for (int j = 0; j < 4; ++j)
        pv[j] = to_bf16(((dt ? ot1 : ot0)[rg * 4 + j]) * inv);
      *reinterpret_cast<bf16x4*>(orow + dt * 32 + rg * 8 + 4 * hi) = pv;
    }
  }
}

extern "C" void kernel_launch(void* const* d_in, const int* in_sizes, int n_in,
                              void* d_out, int out_size, void* d_ws, size_t ws_size,
                              hipStream_t stream) {
  const float* x      = (const float*)d_in[0];
  const float* w_attn = (const float*)d_in[1];
  const float* b_attn = (const float*)d_in[2];
  const float* w_proj = (const float*)d_in[3];
  const float* b_proj = (const float*)d_in[4];
  float* out = (float*)d_out;

  char* ws = (char*)d_ws;
  size_t off = 0;
  bf16* xb  = (bf16*)(ws + off); off += (size_t)M_ * K_ * 2;      // 16 MiB (reused as attn_out)
  bf16* wta = (bf16*)(ws + off); off += (size_t)NQKV * K_ * 2;    // 6 MiB  [3072][1024]
  bf16* wtp = (bf16*)(ws + off); off += (size_t)C_ * K_ * 2;      // 2 MiB  [1024][1024]
  bf16* qb  = (bf16*)(ws + off); off += (size_t)M_ * C_ * 2;      // 16 MiB [B,H,T,D]
  bf16* kb  = (bf16*)(ws + off); off += (size_t)M_ * C_ * 2;      // 16 MiB [B,H,T,D]
  bf16* vtb = (bf16*)(ws + off); off += (size_t)M_ * C_ * 2;      // 16 MiB [B,H,D,T]
  bf16* attn_out = xb;  // x no longer needed once QKV GEMM is done

  cvt_x_kernel<<<(M_ * K_) / (4 * 256), 256, 0, stream>>>(x, xb);
  transpose_cvt_kernel<<<dim3(NQKV / 32, K_ / 32), dim3(32, 8), 0, stream>>>(w_attn, wta, K_, NQKV);
  transpose_cvt_kernel<<<dim3(C_ / 32, K_ / 32), dim3(32, 8), 0, stream>>>(w_proj, wtp, K_, C_);
  gemm_kernel<true><<<dim3(M_ / 128, NQKV / 128), 256, 0, stream>>>(
      xb, wta, b_attn, qb, kb, vtb, nullptr);
  attn_kernel<<<1024, 256, 0, stream>>>(qb, kb, vtb, attn_out);
  gemm_kernel<false><<<dim3(M_ / 128, C_ / 128), 256, 0, stream>>>(
      attn_out, wtp, b_proj, nullptr, nullptr, nullptr, out);
}

// Round 18
// 258.230 us; speedup vs baseline: 1.2408x; 1.2408x over previous
//
#include <hip/hip_runtime.h>
#include <hip/hip_bf16.h>
#include <math.h>

typedef __bf16 bf16;
typedef __bf16 bf16x8 __attribute__((ext_vector_type(8)));
typedef __bf16 bf16x4 __attribute__((ext_vector_type(4)));
typedef __bf16 bf16x2 __attribute__((ext_vector_type(2)));
typedef float f32x4 __attribute__((ext_vector_type(4)));
typedef float f32x16 __attribute__((ext_vector_type(16)));
typedef int int4v __attribute__((ext_vector_type(4)));

static constexpr int B_ = 4, T_ = 2048, C_ = 1024, H_ = 16, D_ = 64;
static constexpr int M_ = B_ * T_;   // 8192 rows
static constexpr int NQKV = 3 * C_;  // 3072
static constexpr int K_ = C_;        // 1024 (GEMM reduction dim)

__device__ __forceinline__ bf16 to_bf16(float f) { return (bf16)f; }

// async global->LDS, 16B per lane; LDS dest = wave-uniform base + lane*16
__device__ __forceinline__ void gload_lds16(const void* g, void* l) {
  __builtin_amdgcn_global_load_lds(
      (const __attribute__((address_space(1))) void*)g,
      (__attribute__((address_space(3))) void*)l, 16, 0, 0);
}

// ---------------- fp32 -> bf16 elementwise convert (x) ----------------
__global__ void cvt_x_kernel(const float* __restrict__ in, bf16* __restrict__ out) {
  int i = (blockIdx.x * blockDim.x + threadIdx.x) * 4;
  float4 v = *reinterpret_cast<const float4*>(in + i);
  bf16x4 o;
  o[0] = to_bf16(v.x); o[1] = to_bf16(v.y); o[2] = to_bf16(v.z); o[3] = to_bf16(v.w);
  *reinterpret_cast<bf16x4*>(out + i) = o;
}

// ------------- fp32 [ROWS][COLS] -> bf16 [COLS][ROWS] transpose -------------
__global__ void transpose_cvt_kernel(const float* __restrict__ in, bf16* __restrict__ out,
                                     int ROWS, int COLS) {
  __shared__ float tile[32][33];
  int c0 = blockIdx.x * 32, r0 = blockIdx.y * 32;
  int tx = threadIdx.x, ty = threadIdx.y;  // 32 x 8
#pragma unroll
  for (int i = 0; i < 32; i += 8)
    tile[ty + i][tx] = in[(size_t)(r0 + ty + i) * COLS + c0 + tx];
  __syncthreads();
#pragma unroll
  for (int i = 0; i < 32; i += 8)
    out[(size_t)(c0 + ty + i) * ROWS + r0 + tx] = to_bf16(tile[tx][ty + i]);
}

// ---------------- bf16 MFMA GEMM v2: 128x128 tile, BK=64 ----------------
// global_load_lds w16 staging into LINEAR LDS [128][64] with XOR k-slot swizzle
// (G21: inverse-swizzled global source + swizzled ds_read; involution = XOR).
template <bool QKV>
__global__ __launch_bounds__(256) void gemm_kernel(
    const bf16* __restrict__ A, const bf16* __restrict__ Bt,
    const float* __restrict__ bias,
    bf16* __restrict__ qo, bf16* __restrict__ ko, bf16* __restrict__ vo,
    float* __restrict__ co) {
  __shared__ bf16 As[128 * 64];  // row*64 + slot*8 elems; row stride 128B
  __shared__ bf16 Bs[128 * 64];
  const int bm = blockIdx.x, bn = blockIdx.y;
  const int tid = threadIdx.x;
  const int lane = tid & 63, wave = tid >> 6;
  const int wm = wave >> 1, wn = wave & 1;  // 2x2 waves, 64x64 each
  const int l15 = lane & 15, lg = lane >> 4;
  const int l3 = lane >> 3, l7 = lane & 7;
  const int sslot = l7 ^ l3;  // source k-slot: row&7 == l3 for all staging calls

  // staging source pointers: wave stages rows [wave*32, wave*32+32), 4 calls x 8 rows
  const bf16* asrc[4];
  const bf16* bsrc[4];
#pragma unroll
  for (int j = 0; j < 4; ++j) {
    const int row = wave * 32 + j * 8 + l3;
    asrc[j] = A + (size_t)(bm * 128 + row) * K_ + sslot * 8;
    bsrc[j] = Bt + (size_t)(bn * 128 + row) * K_ + sslot * 8;
  }

  f32x4 acc[4][4] = {};

  for (int k0 = 0; k0 < K_; k0 += 64) {
#pragma unroll
    for (int j = 0; j < 4; ++j) {
      gload_lds16(asrc[j] + k0, &As[(wave * 32 + j * 8) * 64]);
      gload_lds16(bsrc[j] + k0, &Bs[(wave * 32 + j * 8) * 64]);
    }
    __syncthreads();  // drains vmcnt (global_load_lds) before reads
    bf16x8 af[4][2], bf[4][2];
#pragma unroll
    for (int m = 0; m < 4; ++m)
#pragma unroll
      for (int kk = 0; kk < 2; ++kk)
        af[m][kk] = *reinterpret_cast<const bf16x8*>(
            &As[(wm * 64 + m * 16 + l15) * 64 + (((kk * 4 + lg) ^ (l15 & 7)) * 8)]);
#pragma unroll
    for (int n = 0; n < 4; ++n)
#pragma unroll
      for (int kk = 0; kk < 2; ++kk)
        bf[n][kk] = *reinterpret_cast<const bf16x8*>(
            &Bs[(wn * 64 + n * 16 + l15) * 64 + (((kk * 4 + lg) ^ (l15 & 7)) * 8)]);
#pragma unroll
    for (int kk = 0; kk < 2; ++kk)
#pragma unroll
      for (int m = 0; m < 4; ++m)
#pragma unroll
        for (int n = 0; n < 4; ++n)
          acc[m][n] =
              __builtin_amdgcn_mfma_f32_16x16x32_bf16(af[m][kk], bf[n][kk], acc[m][n], 0, 0, 0);
    __syncthreads();  // protect LDS from next-step overwrite
  }

  const int colbase = bn * 128 + wn * 64;
  const int rowbase = bm * 128 + wm * 64;
  if (QKV) {
    const int sec = (bn * 128) >> 10;  // 0=q 1=k 2=v (block-uniform)
#pragma unroll
    for (int n = 0; n < 4; ++n) {
      const int col = colbase + n * 16 + l15;
      const float bv = bias[col];
      const int cc = col & 1023;
      const int h = cc >> 6, d = cc & 63;
#pragma unroll
      for (int m = 0; m < 4; ++m) {
        const int row0 = rowbase + m * 16 + lg * 4;
        const int b = row0 >> 11, t0 = row0 & 2047;
        if (sec == 2) {
          bf16x4 pv;
#pragma unroll
          for (int r = 0; r < 4; ++r) pv[r] = to_bf16(acc[m][n][r] + bv);
          *reinterpret_cast<bf16x4*>(&vo[((size_t)(b * 16 + h) * 64 + d) * 2048 + t0]) = pv;
        } else if (sec == 0) {
#pragma unroll
          for (int r = 0; r < 4; ++r)
            qo[((size_t)(b * 16 + h) * 2048 + t0 + r) * 64 + d] =
                to_bf16((acc[m][n][r] + bv) * 0.125f);
        } else {
#pragma unroll
          for (int r = 0; r < 4; ++r)
            ko[((size_t)(b * 16 + h) * 2048 + t0 + r) * 64 + d] = to_bf16(acc[m][n][r] + bv);
        }
      }
    }
  } else {
#pragma unroll
    for (int n = 0; n < 4; ++n) {
      const int col = colbase + n * 16 + l15;
      const float bv = bias[col];
#pragma unroll
      for (int m = 0; m < 4; ++m) {
#pragma unroll
        for (int r = 0; r < 4; ++r) {
          const int row = rowbase + m * 16 + lg * 4 + r;
          co[(size_t)row * 1024 + col] = acc[m][n][r] + bv;
        }
      }
    }
  }
}

// ---------------- causal flash attention v3 ----------------
// v3: K/V tiles staged in LDS ONCE per block via global_load_lds (full-line
// coalesced, shared by all 4 waves) + XOR-swizzled ds_read_b128 fragments.
// R14 diagnosis: per-wave strided global frag loads = 32 scattered 32B
// transactions/instr; TA pipe saturated (MfmaUtil 10%, VALU 30%, 60% no-issue).
// R14's K-register prefetch REVERTED (regressed: +16 VGPR, 32 v_mov/iter).
__device__ __forceinline__ int pack_bf2(float lo, float hi) {
  bf16x2 t; t[0] = (bf16)lo; t[1] = (bf16)hi;
  return __builtin_bit_cast(int, t);
}

template <int R0>
__device__ __forceinline__ bf16x8 pack_pstep(f32x16 pf, int h) {
  int a  = pack_bf2(pf[R0 + 0], pf[R0 + 1]);
  int b2 = pack_bf2(pf[R0 + 2], pf[R0 + 3]);
  int c  = pack_bf2(pf[R0 + 4], pf[R0 + 5]);
  int d2 = pack_bf2(pf[R0 + 6], pf[R0 + 7]);
  int pa = __shfl_xor(a, 32);
  int pb = __shfl_xor(b2, 32);
  int pc = __shfl_xor(c, 32);
  int pd = __shfl_xor(d2, 32);
  int4v pi = {h ? pc : a, h ? pd : b2, h ? c : pa, h ? d2 : pb};
  return __builtin_bit_cast(bf16x8, pi);
}

__global__ __launch_bounds__(256) void attn_kernel(
    const bf16* __restrict__ q, const bf16* __restrict__ k,
    const bf16* __restrict__ vT, bf16* __restrict__ o) {
  // [64 rows][128B] per tile, double-buffered; row r at byte r*128.
  __shared__ bf16 Ks[2][64 * 64];
  __shared__ bf16 Vs[2][64 * 64];
  const int bid = blockIdx.x;            // 0..1023
  const int xcd = bid & 7;
  const int local = bid >> 3;            // 0..127 within XCD
  const int qt = 15 - (local >> 3);      // long-first (LPT)
  const int bh = xcd * 8 + (local & 7);  // 8 heads per XCD -> KV L2-resident
  const int tid = threadIdx.x;
  const int lane = tid & 63, w = tid >> 6;
  const int l31 = lane & 31, hi = lane >> 5;
  const int l8r = lane >> 3, l8c = lane & 7;
  const int soff = (l8c * 16) ^ ((l8r & 7) << 4);  // pre-swizzled source byte (G21)
  const int rsw = (l31 & 7) << 4;                  // read-side XOR term
  const char* qp = (const char*)(q + (size_t)bh * T_ * D_);
  const char* kp = (const char*)(k + (size_t)bh * T_ * D_);
  const char* vp = (const char*)(vT + (size_t)bh * D_ * T_);
  const int lofKQ = l31 * 128 + hi * 16;  // Q row stride 128B (global, once)
  const int bb = bh >> 4, hh = bh & 15;
  bf16* obase = o + (size_t)bb * T_ * C_ + hh * 64;

  const int qrow0 = qt * 128 + w * 32;
  const int qg = qrow0 + l31;
  const int nt = 2 * qt + 2;  // shared tile count (max over waves)

  bf16x8 qf[4];
#pragma unroll
  for (int s = 0; s < 4; ++s)
    qf[s] = *reinterpret_cast<const bf16x8*>(qp + (size_t)qrow0 * 128 + s * 32 + lofKQ);

  f32x16 ot0 = {}, ot1 = {};
  float mrun = -INFINITY, lrun = 0.f;

  // stage tile t into buffer buf: 16 calls total (8 K + 8 V), 4 per wave.
  // call c covers rows c*8..c*8+8; lane: row +l8r, 16B slot l8c (swizzled src).
  auto STAGE = [&](int t, int buf) {
    const int tb = t * 64;
#pragma unroll
    for (int j = 0; j < 2; ++j) {
      const int c = w * 2 + j;
      gload_lds16(kp + (size_t)(tb + c * 8 + l8r) * 128 + soff, &Ks[buf][c * 8 * 64]);
      gload_lds16(vp + (size_t)(c * 8 + l8r) * 4096 + (size_t)tb * 2 + soff, &Vs[buf][c * 8 * 64]);
    }
  };

  STAGE(0, 0);
  __syncthreads();

  for (int t = 0; t < nt; ++t) {
    const int tb = t * 64;
    const int buf = t & 1;
    if (t + 1 < nt) STAGE(t + 1, buf ^ 1);  // issue next tile early (latency under compute)
    if (tb < qrow0 + 32) {                  // this wave has work in tile t
      const char* kb = (const char*)&Ks[buf][0];
      const char* vb = (const char*)&Vs[buf][0];
      // K fragments (swizzled LDS read), QK^T swapped: lane -> 32 k-vals for q=l31
      f32x16 st0 = {}, st1 = {};
#pragma unroll
      for (int s = 0; s < 4; ++s) {
        bf16x8 k0 = *reinterpret_cast<const bf16x8*>(kb + l31 * 128 + ((s * 32 + hi * 16) ^ rsw));
        bf16x8 k1 =
            *reinterpret_cast<const bf16x8*>(kb + (32 + l31) * 128 + ((s * 32 + hi * 16) ^ rsw));
        st0 = __builtin_amdgcn_mfma_f32_32x32x16_bf16(k0, qf[s], st0, 0, 0, 0);
        st1 = __builtin_amdgcn_mfma_f32_32x32x16_bf16(k1, qf[s], st1, 0, 0, 0);
      }
      // V fragments (read early; latency hides under softmax)
      bf16x8 va[2][4];
#pragma unroll
      for (int dt = 0; dt < 2; ++dt)
#pragma unroll
        for (int s = 0; s < 4; ++s)
          va[dt][s] = *reinterpret_cast<const bf16x8*>(
              vb + (dt * 32 + l31) * 128 + ((s * 32 + hi * 16) ^ rsw));
      // causal mask (diagonal tiles only)
      if (tb + 63 > qrow0) {
#pragma unroll
        for (int r = 0; r < 16; ++r) {
          const int koff = (r & 3) + 8 * (r >> 2) + 4 * hi;
          if (tb + koff > qg) st0[r] = -1e30f;
          if (tb + 32 + koff > qg) st1[r] = -1e30f;
        }
      }
      // row max: in-register tree + partner (lane^32) combine
      float mx[16];
#pragma unroll
      for (int r = 0; r < 16; ++r) mx[r] = fmaxf(st0[r], st1[r]);
#pragma unroll
      for (int d = 8; d > 0; d >>= 1)
#pragma unroll
        for (int r = 0; r < d; ++r) mx[r] = fmaxf(mx[r], mx[r + d]);
      const float pmax = fmaxf(mx[0], __shfl_xor(mx[0], 32));
      // defer-max (T13): skip O-rescale when max growth small
      if (__any(pmax > mrun + 8.f)) {
        const float mnew = fmaxf(mrun, pmax);
        const float corr = __expf(mrun - mnew);
        lrun *= corr;
#pragma unroll
        for (int r = 0; r < 16; ++r) { ot0[r] *= corr; ot1[r] *= corr; }
        mrun = mnew;
      }
#pragma unroll
      for (int r = 0; r < 16; ++r) {
        st0[r] = __expf(st0[r] - mrun);
        st1[r] = __expf(st1[r] - mrun);
      }
      // row sum: in-register tree + partner combine
      float sm[16];
#pragma unroll
      for (int r = 0; r < 16; ++r) sm[r] = st0[r] + st1[r];
#pragma unroll
      for (int d = 8; d > 0; d >>= 1)
#pragma unroll
        for (int r = 0; r < d; ++r) sm[r] += sm[r + d];
      lrun += sm[0] + __shfl_xor(sm[0], 32);
      // P -> bf16 B-fragments (pack + lane^32 exchange, no LDS)
      bf16x8 pb[4];
      pb[0] = pack_pstep<0>(st0, hi);
      pb[1] = pack_pstep<8>(st0, hi);
      pb[2] = pack_pstep<0>(st1, hi);
      pb[3] = pack_pstep<8>(st1, hi);
      // PV: O^T[d][q] — output column = q = l31, same as softmax state
#pragma unroll
      for (int s = 0; s < 4; ++s) {
        ot0 = __builtin_amdgcn_mfma_f32_32x32x16_bf16(va[0][s], pb[s], ot0, 0, 0, 0);
        ot1 = __builtin_amdgcn_mfma_f32_32x32x16_bf16(va[1][s], pb[s], ot1, 0, 0, 0);
      }
    }
    __syncthreads();  // readers done with buf; staging of t+1 drained
  }

  const float inv = 1.f / lrun;
  bf16* orow = obase + (size_t)qg * C_;
#pragma unroll
  for (int dt = 0; dt < 2; ++dt) {
#pragma unroll
    for (int rg = 0; rg < 4; ++rg) {
      bf16x4 pv;
#pragma unroll
      for (int j = 0; j < 4; ++j)
        pv[j] = to_bf16(((dt ? ot1 : ot0)[rg * 4 + j]) * inv);
      *reinterpret_cast<bf16x4*>(orow + dt * 32 + rg * 8 + 4 * hi) = pv;
    }
  }
}

extern "C" void kernel_launch(void* const* d_in, const int* in_sizes, int n_in,
                              void* d_out, int out_size, void* d_ws, size_t ws_size,
                              hipStream_t stream) {
  const float* x      = (const float*)d_in[0];
  const float* w_attn = (const float*)d_in[1];
  const float* b_attn = (const float*)d_in[2];
  const float* w_proj = (const float*)d_in[3];
  const float* b_proj = (const float*)d_in[4];
  float* out = (float*)d_out;

  char* ws = (char*)d_ws;
  size_t off = 0;
  bf16* xb  = (bf16*)(ws + off); off += (size_t)M_ * K_ * 2;      // 16 MiB (reused as attn_out)
  bf16* wta = (bf16*)(ws + off); off += (size_t)NQKV * K_ * 2;    // 6 MiB  [3072][1024]
  bf16* wtp = (bf16*)(ws + off); off += (size_t)C_ * K_ * 2;      // 2 MiB  [1024][1024]
  bf16* qb  = (bf16*)(ws + off); off += (size_t)M_ * C_ * 2;      // 16 MiB [B,H,T,D]
  bf16* kb  = (bf16*)(ws + off); off += (size_t)M_ * C_ * 2;      // 16 MiB [B,H,T,D]
  bf16* vtb = (bf16*)(ws + off); off += (size_t)M_ * C_ * 2;      // 16 MiB [B,H,D,T]
  bf16* attn_out = xb;  // x no longer needed once QKV GEMM is done

  cvt_x_kernel<<<(M_ * K_) / (4 * 256), 256, 0, stream>>>(x, xb);
  transpose_cvt_kernel<<<dim3(NQKV / 32, K_ / 32), dim3(32, 8), 0, stream>>>(w_attn, wta, K_, NQKV);
  transpose_cvt_kernel<<<dim3(C_ / 32, K_ / 32), dim3(32, 8), 0, stream>>>(w_proj, wtp, K_, C_);
  gemm_kernel<true><<<dim3(M_ / 128, NQKV / 128), 256, 0, stream>>>(
      xb, wta, b_attn, qb, kb, vtb, nullptr);
  attn_kernel<<<1024, 256, 0, stream>>>(qb, kb, vtb, attn_out);
  gemm_kernel<false><<<dim3(M_ / 128, C_ / 128), 256, 0, stream>>>(
      attn_out, wtp, b_proj, nullptr, nullptr, nullptr, out);
}